// Round 1
// baseline (147.831 us; speedup 1.0000x reference)
//
#include <hip/hip_runtime.h>
#include <math.h>

// Problem constants (B=16, C=64, H=W=112, WS=7 -> 784 tiles of 16x16 pixels)
#define CC    64      // input/output channels
#define CF    16      // feature channels
#define NPIX  256     // pixels per tile (16x16)
#define KK    9       // top-k
#define HWQ   12544   // 112*112
#define WWQ   112

__global__ __launch_bounds__(256) void gnn_fused(
    const float* __restrict__ x_in, const float* __restrict__ Wf,
    const float* __restrict__ bf,   const float* __restrict__ Wp,
    const float* __restrict__ bp,   const float* __restrict__ W1,
    const float* __restrict__ b1,   const float* __restrict__ W2,
    const float* __restrict__ b2,   const float* __restrict__ sigma_p,
    const float* __restrict__ alpha_p, float* __restrict__ y)
{
    __shared__ float s_xf[NPIX][CF];   // raw features per pixel
    __shared__ float s_xn[NPIX][CF];   // normalized features
    __shared__ float s_W[CC * CF];     // Wf (16x64) then reused for Wp (64x16)
    __shared__ float s_table[451];     // exp(-d^2/(2 sigma^2)) for integer d^2
    __shared__ float s_bias[CC];       // bf (16) then reused for bp (64)

    const int bpi = blockIdx.x;        // 0..783
    const int bb  = bpi / 49;
    const int ssb = bpi % 49;
    const int s1  = ssb / 7, s2 = ssb % 7;
    const int tid = threadIdx.x;       // pixel index n in tile
    const int pi  = tid >> 4, pj = tid & 15;
    const int gy  = s1 * 16 + pi, gx = s2 * 16 + pj;

    const float alpha = alpha_p[0];
    const float oma   = 1.0f - alpha;
    const float sig   = sigma_p[0];
    const float denom = 2.0f * sig * sig;

    // ---- stage Wf, bf, distance-sim table ----
    for (int t = tid; t < CF * CC; t += NPIX) s_W[t] = Wf[t];
    if (tid < CF) s_bias[tid] = bf[tid];
    for (int t = tid; t < 451; t += NPIX) {
        float dd = sqrtf((float)t);               // dist = sqrt(d2)
        s_table[t] = expf((-(dd * dd)) / denom);  // exp(-dist^2 / (2 sigma^2))
    }
    // MLP weights to registers (broadcast loads)
    float W1r[8], b1r[4], W2r[4];
    #pragma unroll
    for (int h = 0; h < 8; ++h) W1r[h] = W1[h];
    #pragma unroll
    for (int h = 0; h < 4; ++h) { b1r[h] = b1[h]; W2r[h] = W2[h]; }
    const float b2r = b2[0];
    __syncthreads();

    // ---- phase 1: f = Wf @ x + bf  (64 -> 16), then normalize ----
    const float* xb = x_in + (size_t)bb * CC * HWQ + (size_t)gy * WWQ + gx;
    float fv[CF];
    #pragma unroll
    for (int o = 0; o < CF; ++o) fv[o] = 0.0f;
    for (int c = 0; c < CC; ++c) {
        float xv = xb[(size_t)c * HWQ];
        #pragma unroll
        for (int o = 0; o < CF; ++o)
            fv[o] = fmaf(xv, s_W[o * CC + c], fv[o]);
    }
    #pragma unroll
    for (int o = 0; o < CF; ++o) fv[o] += s_bias[o];

    float ss2 = 0.0f;
    #pragma unroll
    for (int o = 0; o < CF; ++o) ss2 = fmaf(fv[o], fv[o], ss2);
    float nrm = fmaxf(sqrtf(ss2), 1e-8f);

    float xnr[CF];
    #pragma unroll
    for (int o = 0; o < CF; ++o) {
        xnr[o] = fv[o] / nrm;
        s_xf[tid][o] = fv[o];
        s_xn[tid][o] = xnr[o];
    }
    __syncthreads();

    // ---- phase 2: combined similarity + running top-9 (stable, lower index wins ties) ----
    float tv[KK]; int ti[KK];
    #pragma unroll
    for (int k = 0; k < KK; ++k) { tv[k] = -INFINITY; ti[k] = 0; }

    for (int m = 0; m < NPIX; ++m) {
        const float4* xm4 = reinterpret_cast<const float4*>(&s_xn[m][0]);
        float4 a0 = xm4[0], a1 = xm4[1], a2 = xm4[2], a3 = xm4[3];
        float dot = 0.0f;
        dot = fmaf(xnr[0],  a0.x, dot); dot = fmaf(xnr[1],  a0.y, dot);
        dot = fmaf(xnr[2],  a0.z, dot); dot = fmaf(xnr[3],  a0.w, dot);
        dot = fmaf(xnr[4],  a1.x, dot); dot = fmaf(xnr[5],  a1.y, dot);
        dot = fmaf(xnr[6],  a1.z, dot); dot = fmaf(xnr[7],  a1.w, dot);
        dot = fmaf(xnr[8],  a2.x, dot); dot = fmaf(xnr[9],  a2.y, dot);
        dot = fmaf(xnr[10], a2.z, dot); dot = fmaf(xnr[11], a2.w, dot);
        dot = fmaf(xnr[12], a3.x, dot); dot = fmaf(xnr[13], a3.y, dot);
        dot = fmaf(xnr[14], a3.z, dot); dot = fmaf(xnr[15], a3.w, dot);

        int di = pi - (m >> 4);
        int dj = pj - (m & 15);
        float sd = s_table[di * di + dj * dj];
        // combined = alpha*sf + (1-alpha)*sd, no FMA contraction (match reference rounding)
        float comb = __fadd_rn(__fmul_rn(alpha, dot), __fmul_rn(oma, sd));

        if (comb > tv[KK - 1]) {
            float cv = comb; int ci = m;
            #pragma unroll
            for (int t = KK - 1; t >= 0; --t) {
                bool g = (cv > tv[t]);
                float ov = tv[t]; int oi = ti[t];
                if (g) {
                    if (t + 1 < KK) { tv[t + 1] = ov; ti[t + 1] = oi; }
                    tv[t] = cv; ti[t] = ci;
                }
            }
        }
    }

    // ---- phase 3: edge MLP weights + message aggregation ----
    float wk[KK];
    float wsum = 0.0f;
    #pragma unroll
    for (int k = 0; k < KK; ++k) {
        int m = ti[k];
        int di = pi - (m >> 4);
        int dj = pj - (m & 15);
        float sd = s_table[di * di + dj * dj];
        // recover sim_feat from stored combined value (exact when alpha=0.5)
        float sf = (tv[k] - __fmul_rn(oma, sd)) / alpha;
        float hsum = b2r;
        #pragma unroll
        for (int h = 0; h < 4; ++h) {
            float z  = fmaf(sf, W1r[2 * h], fmaf(sd, W1r[2 * h + 1], b1r[h]));
            float sg = 1.0f / (1.0f + expf(-z));
            hsum = fmaf(z * sg, W2r[h], hsum);   // silu(z) = z*sigmoid(z)
        }
        float wg = 1.0f / (1.0f + expf(-hsum));
        wk[k] = wg;
        wsum += wg;
    }
    wsum += 1e-12f;

    float outv[CF];
    #pragma unroll
    for (int o = 0; o < CF; ++o) outv[o] = 0.0f;
    #pragma unroll
    for (int k = 0; k < KK; ++k) {
        float wn = wk[k] / wsum;
        int m = ti[k];
        const float4* xf4 = reinterpret_cast<const float4*>(&s_xf[m][0]);
        float4 m0 = xf4[0], m1 = xf4[1], m2 = xf4[2], m3 = xf4[3];
        outv[0]  = fmaf(wn, m0.x, outv[0]);  outv[1]  = fmaf(wn, m0.y, outv[1]);
        outv[2]  = fmaf(wn, m0.z, outv[2]);  outv[3]  = fmaf(wn, m0.w, outv[3]);
        outv[4]  = fmaf(wn, m1.x, outv[4]);  outv[5]  = fmaf(wn, m1.y, outv[5]);
        outv[6]  = fmaf(wn, m1.z, outv[6]);  outv[7]  = fmaf(wn, m1.w, outv[7]);
        outv[8]  = fmaf(wn, m2.x, outv[8]);  outv[9]  = fmaf(wn, m2.y, outv[9]);
        outv[10] = fmaf(wn, m2.z, outv[10]); outv[11] = fmaf(wn, m2.w, outv[11]);
        outv[12] = fmaf(wn, m3.x, outv[12]); outv[13] = fmaf(wn, m3.y, outv[13]);
        outv[14] = fmaf(wn, m3.z, outv[14]); outv[15] = fmaf(wn, m3.w, outv[15]);
    }

    // ---- phase 4: restage Wp/bp, project 16 -> 64, store ----
    __syncthreads();
    for (int t = tid; t < CC * CF; t += NPIX) s_W[t] = Wp[t];
    if (tid < CC) s_bias[tid] = bp[tid];
    __syncthreads();

    float* yb = y + (size_t)bb * CC * HWQ + (size_t)gy * WWQ + gx;
    for (int o = 0; o < CC; ++o) {
        float acc = 0.0f;
        #pragma unroll
        for (int c = 0; c < CF; ++c)
            acc = fmaf(outv[c], s_W[o * CF + c], acc);
        yb[(size_t)o * HWQ] = acc + s_bias[o];
    }
}

extern "C" void kernel_launch(void* const* d_in, const int* in_sizes, int n_in,
                              void* d_out, int out_size, void* d_ws, size_t ws_size,
                              hipStream_t stream) {
    const float* x_in  = (const float*)d_in[0];
    const float* Wf    = (const float*)d_in[1];
    const float* bf    = (const float*)d_in[2];
    const float* Wp    = (const float*)d_in[3];
    const float* bp    = (const float*)d_in[4];
    const float* W1    = (const float*)d_in[5];
    const float* b1    = (const float*)d_in[6];
    const float* W2    = (const float*)d_in[7];
    const float* b2    = (const float*)d_in[8];
    const float* sigma = (const float*)d_in[9];
    const float* alpha = (const float*)d_in[10];
    float* y = (float*)d_out;

    gnn_fused<<<784, 256, 0, stream>>>(x_in, Wf, bf, Wp, bp, W1, b1, W2, b2,
                                       sigma, alpha, y);
}